// Round 3
// baseline (88.080 us; speedup 1.0000x reference)
//
#include <hip/hip_runtime.h>
#include <hip/hip_bf16.h>

#define N_ 4096
#define D_ 768
#define NCLS 128
#define BM 128
#define BN 128
#define BK 32
#define NT 24  // D_/BK K-steps

typedef __bf16 bf16x8 __attribute__((ext_vector_type(8)));
typedef float f32x4 __attribute__((ext_vector_type(4)));

__device__ __forceinline__ void gload16(const unsigned short* g, unsigned short* l) {
  __builtin_amdgcn_global_load_lds(
      (const __attribute__((address_space(1))) unsigned int*)g,
      (__attribute__((address_space(3))) unsigned int*)l, 16, 0, 0);
}

// Normalize both embedding matrices (blocks [0,N) -> img, [N,2N) -> txt).
// 192 threads: one float4 (16B) load + one ushort4 (8B) store per lane.
__global__ __launch_bounds__(192) void normalize_kernel(
    const float* __restrict__ img, const float* __restrict__ txt,
    __hip_bfloat16* __restrict__ img_nb, __hip_bfloat16* __restrict__ txt_nb) {
  int b = blockIdx.x;
  const float* s;
  __hip_bfloat16* d;
  if (b < N_) {
    s = img + (size_t)b * D_;
    d = img_nb + (size_t)b * D_;
  } else {
    s = txt + (size_t)(b - N_) * D_;
    d = txt_nb + (size_t)(b - N_) * D_;
  }
  int tid = threadIdx.x;
  float4 v = ((const float4*)s)[tid];
  float ss = v.x * v.x + v.y * v.y + v.z * v.z + v.w * v.w;
#pragma unroll
  for (int m = 32; m; m >>= 1) ss += __shfl_xor(ss, m);
  __shared__ float wsum[3];
  int lane = tid & 63, w = tid >> 6;
  if (lane == 0) wsum[w] = ss;
  __syncthreads();
  float inv = 1.0f / fmaxf(sqrtf(wsum[0] + wsum[1] + wsum[2]), 1e-8f);
  ushort4 o;
  o.x = __bfloat16_as_ushort(__float2bfloat16(v.x * inv));
  o.y = __bfloat16_as_ushort(__float2bfloat16(v.y * inv));
  o.z = __bfloat16_as_ushort(__float2bfloat16(v.z * inv));
  o.w = __bfloat16_as_ushort(__float2bfloat16(v.w * inv));
  ((ushort4*)d)[tid] = o;
}

// GEMM with fused exp-sum epilogue. LDS per tile: [g=k/8][row][8 bf16]
// chunk-linear (global_load_lds-fillable, conflict-free ds_read_b128),
// double-buffered: prefetch t+1 issued before compute of t (T3-min 2-phase).
__global__ __launch_bounds__(256) void gemm_epi_kernel(
    const unsigned short* __restrict__ A, const unsigned short* __restrict__ B,
    const int* __restrict__ labels, float* __restrict__ row_part,
    float* __restrict__ col_part, float* __restrict__ S_part) {
  __shared__ __align__(16) unsigned short As[2][4096];
  __shared__ __align__(16) unsigned short Bs[2][4096];
  __shared__ int labR[BM], labC[BN];
  __shared__ float rbuf[2][BM], cbuf[2][BN];
  __shared__ float sbuf[4];

  const int bx = blockIdx.x, by = blockIdx.y;
  const int tid = threadIdx.x;
  const int lane = tid & 63, wave = tid >> 6;
  const int wr = wave >> 1, wc = wave & 1;
  const int g = lane >> 4, fr = lane & 15;
  const int rowBase = by * BM, colBase = bx * BN;

  if (tid < BM) labR[tid] = labels[rowBase + tid];
  else labC[tid - BM] = labels[colBase + tid - BM];

  // staging coordinates for this thread (fixed across K-steps)
  int c0_0 = wave * 64;        // chunks [0,256)
  int c0_1 = 256 + wave * 64;  // chunks [256,512)
  int cA0 = c0_0 + lane, cA1 = c0_1 + lane;
  int r0 = cA0 & 127, g0 = cA0 >> 7;
  int r1 = cA1 & 127, g1 = cA1 >> 7;
  const unsigned short* srcA0 = A + (size_t)(rowBase + r0) * D_ + g0 * 8;
  const unsigned short* srcA1 = A + (size_t)(rowBase + r1) * D_ + g1 * 8;
  const unsigned short* srcB0 = B + (size_t)(colBase + r0) * D_ + g0 * 8;
  const unsigned short* srcB1 = B + (size_t)(colBase + r1) * D_ + g1 * 8;

  f32x4 acc[4][4] = {};

  // prologue: stage tile 0 into buf 0
  gload16(srcA0, &As[0][c0_0 * 8]);
  gload16(srcB0, &Bs[0][c0_0 * 8]);
  gload16(srcA1, &As[0][c0_1 * 8]);
  gload16(srcB1, &Bs[0][c0_1 * 8]);
  __syncthreads();  // vmcnt(0) drain + barrier: tile 0 resident

#pragma unroll 2
  for (int t = 0; t < NT; ++t) {
    const int cur = t & 1;
    if (t + 1 < NT) {  // prefetch t+1 into the other buffer (overlaps compute)
      const int k0 = (t + 1) * BK;
      gload16(srcA0 + k0, &As[cur ^ 1][c0_0 * 8]);
      gload16(srcB0 + k0, &Bs[cur ^ 1][c0_0 * 8]);
      gload16(srcA1 + k0, &As[cur ^ 1][c0_1 * 8]);
      gload16(srcB1 + k0, &Bs[cur ^ 1][c0_1 * 8]);
    }
    bf16x8 af[4], bfr[4];
#pragma unroll
    for (int m = 0; m < 4; ++m)
      af[m] = *(const bf16x8*)&As[cur][g * 1024 + (wr * 64 + m * 16 + fr) * 8];
#pragma unroll
    for (int n = 0; n < 4; ++n)
      bfr[n] = *(const bf16x8*)&Bs[cur][g * 1024 + (wc * 64 + n * 16 + fr) * 8];
#pragma unroll
    for (int m = 0; m < 4; ++m)
#pragma unroll
      for (int n = 0; n < 4; ++n)
        acc[m][n] = __builtin_amdgcn_mfma_f32_16x16x32_bf16(af[m], bfr[n], acc[m][n], 0, 0, 0);
    __syncthreads();  // drains prefetch (vmcnt0) + all waves done reading buf cur
  }

  const float scale = 14.285714285714286f;  // 1/0.07
  float sPart = 0.f;
  float colAcc[4] = {0.f, 0.f, 0.f, 0.f};
#pragma unroll
  for (int m = 0; m < 4; ++m) {
    float ra[4] = {0.f, 0.f, 0.f, 0.f};
#pragma unroll
    for (int n = 0; n < 4; ++n) {
      int col = wc * 64 + n * 16 + fr;
      int lc = labC[col];
#pragma unroll
      for (int r = 0; r < 4; ++r) {
        float v = acc[m][n][r] * scale;
        float e = __expf(v);
        ra[r] += e;
        colAcc[n] += e;
        int row = wr * 64 + m * 16 + g * 4 + r;
        if (labR[row] == lc) sPart += v;
      }
    }
#pragma unroll
    for (int r = 0; r < 4; ++r) {
      float x = ra[r];
      x += __shfl_xor(x, 1);
      x += __shfl_xor(x, 2);
      x += __shfl_xor(x, 4);
      x += __shfl_xor(x, 8);
      if (fr == 0) rbuf[wc][wr * 64 + m * 16 + g * 4 + r] = x;
    }
  }
#pragma unroll
  for (int n = 0; n < 4; ++n) {
    float x = colAcc[n];
    x += __shfl_xor(x, 16);
    x += __shfl_xor(x, 32);
    if (g == 0) cbuf[wr][wc * 64 + n * 16 + fr] = x;
  }
  float s = sPart;
#pragma unroll
  for (int m = 32; m; m >>= 1) s += __shfl_xor(s, m);
  if (lane == 0) sbuf[wave] = s;
  __syncthreads();
  if (tid < BM)
    row_part[(size_t)bx * N_ + rowBase + tid] = rbuf[0][tid] + rbuf[1][tid];
  else
    col_part[(size_t)by * N_ + colBase + (tid - BM)] = cbuf[0][tid - BM] + cbuf[1][tid - BM];
  if (tid == 0) S_part[by * 32 + bx] = sbuf[0] + sbuf[1] + sbuf[2] + sbuf[3];
}

// Per-block local histogram; partials out (no atomics, no memset needed)
__global__ __launch_bounds__(256) void reduce_kernel(
    const float* __restrict__ row_part, const float* __restrict__ col_part,
    const float* __restrict__ S_part, const int* __restrict__ labels,
    double* __restrict__ partials) {
  __shared__ int hist[NCLS];
  int tid = threadIdx.x;
  if (tid < NCLS) hist[tid] = 0;
  __syncthreads();
  for (int j = tid; j < N_; j += 256) atomicAdd(&hist[labels[j]], 1);
  __syncthreads();

  int i = blockIdx.x * 256 + tid;  // 0..4095
  float rs = 0.f, cs = 0.f;
#pragma unroll
  for (int b = 0; b < 32; ++b) {
    rs += row_part[(size_t)b * N_ + i];
    cs += col_part[(size_t)b * N_ + i];
  }
  int cnt = hist[labels[i]];
  double term = (double)cnt * ((double)logf(rs) + (double)logf(cs));
  double sterm = (i < 1024) ? (double)S_part[i] : 0.0;
#pragma unroll
  for (int m = 32; m; m >>= 1) {
    term += __shfl_xor(term, m);
    sterm += __shfl_xor(sterm, m);
  }
  __shared__ double tbuf[4], sb[4];
  int lane = tid & 63, w = tid >> 6;
  if (lane == 0) { tbuf[w] = term; sb[w] = sterm; }
  __syncthreads();
  if (tid == 0) {
    partials[blockIdx.x] = tbuf[0] + tbuf[1] + tbuf[2] + tbuf[3];
    partials[16 + blockIdx.x] = sb[0] + sb[1] + sb[2] + sb[3];
  }
}

__global__ void final_kernel(const double* __restrict__ partials, float* __restrict__ out) {
  double t = 0.0, s = 0.0;
#pragma unroll
  for (int i = 0; i < 16; ++i) {
    t += partials[i];
    s += partials[16 + i];
  }
  out[0] = (float)((t - 2.0 * s) / (2.0 * (double)N_));
}

extern "C" void kernel_launch(void* const* d_in, const int* in_sizes, int n_in,
                              void* d_out, int out_size, void* d_ws, size_t ws_size,
                              hipStream_t stream) {
  const float* img = (const float*)d_in[0];
  const float* txt = (const float*)d_in[1];
  const int* labels = (const int*)d_in[2];
  float* out = (float*)d_out;
  char* ws = (char*)d_ws;

  // workspace layout (bytes)
  __hip_bfloat16* img_nb = (__hip_bfloat16*)(ws);             //  6,291,456
  __hip_bfloat16* txt_nb = (__hip_bfloat16*)(ws + 6291456);   //  6,291,456
  float* row_part = (float*)(ws + 12582912);                  //    524,288 (32 x 4096)
  float* col_part = (float*)(ws + 13107200);                  //    524,288
  float* S_part = (float*)(ws + 13631488);                    //      4,096
  double* partials = (double*)(ws + 13635584);                //        256

  normalize_kernel<<<2 * N_, 192, 0, stream>>>(img, txt, img_nb, txt_nb);
  gemm_epi_kernel<<<dim3(32, 32), 256, 0, stream>>>(
      (const unsigned short*)img_nb, (const unsigned short*)txt_nb, labels,
      row_part, col_part, S_part);
  reduce_kernel<<<16, 256, 0, stream>>>(row_part, col_part, S_part, labels, partials);
  final_kernel<<<1, 1, 0, stream>>>(partials, out);
}